// Round 1
// baseline (525.488 us; speedup 1.0000x reference)
//
#include <hip/hip_runtime.h>
#include <cmath>

#define L 96
#define LL (L*L)
#define L3 (L*L*L)
#define NBLK (L3/256)   // 3456, exact

__device__ __forceinline__ float eluf(float x) {
    return x > 0.0f ? x : expm1f(x);
}

// ---------------- bonds: spins -> 12 bond features per voxel ----------------
__global__ __launch_bounds__(256) void bonds_kernel(
    const int* __restrict__ lx, const float* __restrict__ tet,
    float* __restrict__ bonds)
{
    int idx = blockIdx.x * 256 + threadIdx.x;
    int w = idx % L;
    int t = idx / L;
    int h = t % L;
    int d = t / L;

    float t00 = tet[0], t01 = tet[1], t10 = tet[2], t11 = tet[3];
    float d00 = t00*t00 + t01*t01;
    float d01 = t00*t10 + t01*t11;
    float d11 = t10*t10 + t11*t11;

    const int4 sv = *reinterpret_cast<const int4*>(lx + 4*idx);
    int s0 = sv.x, s1 = sv.y, s2 = sv.z, s3 = sv.w;
    int dm = (d == 0) ? L-1 : d-1;
    int hm = (h == 0) ? L-1 : h-1;
    int wm = (w == 0) ? L-1 : w-1;
    // r1 = roll(v1,+1,axis d): needs spin ch1 at (d-1); r2: ch2 at (h-1); r3: ch3 at (w-1)
    int r1 = lx[4*((dm*L + h)*L + w) + 1];
    int r2 = lx[4*((d*L + hm)*L + w) + 2];
    int r3 = lx[4*((d*L + h)*L + wm) + 3];

    auto dot = [&](int a, int b) -> float {
        return (a == b) ? (a ? d11 : d00) : d01;
    };

    float o0  = dot(s0, s1);
    float o1  = dot(s0, s2);
    float o2  = dot(s0, s3);
    float o3  = dot(s0, r1);
    float o4  = dot(s0, r2);
    float o5  = dot(s0, r3);
    float o6  = dot(s1, s2);
    float o7  = dot(s2, s3);
    float o8  = dot(s3, s1);
    float o9  = dot(r1, r2);
    float o10 = dot(r2, r3);
    float o11 = dot(r3, r1);

    float4* bp = reinterpret_cast<float4*>(bonds + 12ull*idx);
    bp[0] = make_float4(o0, o1, o2, o3);
    bp[1] = make_float4(o4, o5, o6, o7);
    bp[2] = make_float4(o8, o9, o10, o11);
}

// ---------------- conv1: 12 -> 16, wrap pad, ELU ----------------
__global__ __launch_bounds__(256) void conv1_kernel(
    const float* __restrict__ x, const float* __restrict__ w1,
    const float* __restrict__ b1, float* __restrict__ y)
{
    int idx = blockIdx.x * 256 + threadIdx.x;
    int w = idx % L;
    int t = idx / L;
    int h = t % L;
    int d = t / L;

    float acc[16];
    #pragma unroll
    for (int o = 0; o < 16; ++o) acc[o] = b1[o];

    for (int kd = 0; kd < 3; ++kd) {
        int dc = d + kd - 1; dc = (dc < 0) ? L-1 : (dc >= L ? 0 : dc);
        for (int kh = 0; kh < 3; ++kh) {
            int hc = h + kh - 1; hc = (hc < 0) ? L-1 : (hc >= L ? 0 : hc);
            for (int kw = 0; kw < 3; ++kw) {
                int wc = w + kw - 1; wc = (wc < 0) ? L-1 : (wc >= L ? 0 : wc);
                const float* xp = x + 12ull*((dc*L + hc)*L + wc);
                float4 a0 = *reinterpret_cast<const float4*>(xp);
                float4 a1 = *reinterpret_cast<const float4*>(xp + 4);
                float4 a2 = *reinterpret_cast<const float4*>(xp + 8);
                float xin[12] = {a0.x,a0.y,a0.z,a0.w,a1.x,a1.y,a1.z,a1.w,a2.x,a2.y,a2.z,a2.w};
                const float* wp = w1 + ((kd*3 + kh)*3 + kw)*192;
                #pragma unroll
                for (int i = 0; i < 12; ++i)
                    #pragma unroll
                    for (int o = 0; o < 16; ++o)
                        acc[o] = fmaf(xin[i], wp[i*16 + o], acc[o]);
            }
        }
    }

    float* yp = y + 16ull*idx;
    #pragma unroll
    for (int o = 0; o < 16; o += 4) {
        *reinterpret_cast<float4*>(yp + o) =
            make_float4(eluf(acc[o]), eluf(acc[o+1]), eluf(acc[o+2]), eluf(acc[o+3]));
    }
}

// ---------------- conv2: 16 -> 32, wrap pad, ELU, fused wd-dot + block reduce ----------------
__global__ __launch_bounds__(256) void conv2_kernel(
    const float* __restrict__ x, const float* __restrict__ w2,
    const float* __restrict__ b2, const float* __restrict__ wd,
    float* __restrict__ partials)
{
    int idx = blockIdx.x * 256 + threadIdx.x;
    int w = idx % L;
    int t = idx / L;
    int h = t % L;
    int d = t / L;

    float acc[32];
    #pragma unroll
    for (int o = 0; o < 32; ++o) acc[o] = b2[o];

    for (int kd = 0; kd < 3; ++kd) {
        int dc = d + kd - 1; dc = (dc < 0) ? L-1 : (dc >= L ? 0 : dc);
        for (int kh = 0; kh < 3; ++kh) {
            int hc = h + kh - 1; hc = (hc < 0) ? L-1 : (hc >= L ? 0 : hc);
            for (int kw = 0; kw < 3; ++kw) {
                int wc = w + kw - 1; wc = (wc < 0) ? L-1 : (wc >= L ? 0 : wc);
                const float* xp = x + 16ull*((dc*L + hc)*L + wc);
                float4 a0 = *reinterpret_cast<const float4*>(xp);
                float4 a1 = *reinterpret_cast<const float4*>(xp + 4);
                float4 a2 = *reinterpret_cast<const float4*>(xp + 8);
                float4 a3 = *reinterpret_cast<const float4*>(xp + 12);
                float xin[16] = {a0.x,a0.y,a0.z,a0.w,a1.x,a1.y,a1.z,a1.w,
                                 a2.x,a2.y,a2.z,a2.w,a3.x,a3.y,a3.z,a3.w};
                const float* wp = w2 + ((kd*3 + kh)*3 + kw)*512;
                #pragma unroll
                for (int i = 0; i < 16; ++i)
                    #pragma unroll
                    for (int o = 0; o < 32; ++o)
                        acc[o] = fmaf(xin[i], wp[i*32 + o], acc[o]);
            }
        }
    }

    // fused: elu, dot with wd
    float s = 0.0f;
    #pragma unroll
    for (int o = 0; o < 32; ++o) s += eluf(acc[o]) * wd[o];

    // block reduce (wave64 shuffle + LDS across 4 waves)
    #pragma unroll
    for (int off = 32; off; off >>= 1) s += __shfl_down(s, off);
    __shared__ float red[4];
    int lane = threadIdx.x & 63;
    int wv   = threadIdx.x >> 6;
    if (lane == 0) red[wv] = s;
    __syncthreads();
    if (threadIdx.x == 0) partials[blockIdx.x] = red[0] + red[1] + red[2] + red[3];
}

// ---------------- final: sum partials, scale by 1/L^3 ----------------
__global__ __launch_bounds__(256) void final_kernel(
    const float* __restrict__ partials, float* __restrict__ out)
{
    float s = 0.0f;
    for (int i = threadIdx.x; i < NBLK; i += 256) s += partials[i];
    #pragma unroll
    for (int off = 32; off; off >>= 1) s += __shfl_down(s, off);
    __shared__ float red[4];
    int lane = threadIdx.x & 63;
    int wv   = threadIdx.x >> 6;
    if (lane == 0) red[wv] = s;
    __syncthreads();
    if (threadIdx.x == 0)
        out[0] = (red[0] + red[1] + red[2] + red[3]) * (1.0f / (float)L3);
}

extern "C" void kernel_launch(void* const* d_in, const int* in_sizes, int n_in,
                              void* d_out, int out_size, void* d_ws, size_t ws_size,
                              hipStream_t stream) {
    const int*   lx  = (const int*)  d_in[0];
    const float* tet = (const float*)d_in[1];
    const float* w1  = (const float*)d_in[2];
    const float* b1  = (const float*)d_in[3];
    const float* w2  = (const float*)d_in[4];
    const float* b2  = (const float*)d_in[5];
    const float* wd  = (const float*)d_in[6];
    float* out = (float*)d_out;

    char* ws = (char*)d_ws;
    float* bonds    = (float*)ws;                                  // L3*12 floats (42.5 MB)
    float* y1       = (float*)(ws + sizeof(float)*12ull*L3);       // L3*16 floats (56.6 MB)
    float* partials = (float*)(ws + sizeof(float)*28ull*L3);       // NBLK floats

    bonds_kernel<<<NBLK, 256, 0, stream>>>(lx, tet, bonds);
    conv1_kernel<<<NBLK, 256, 0, stream>>>(bonds, w1, b1, y1);
    conv2_kernel<<<NBLK, 256, 0, stream>>>(y1, w2, b2, wd, partials);
    final_kernel<<<1, 256, 0, stream>>>(partials, out);
}

// Round 2
// 204.042 us; speedup vs baseline: 2.5754x; 2.5754x over previous
//
#include <hip/hip_runtime.h>
#include <hip/hip_bf16.h>
#include <cmath>

#define L 96
#define L3 (L*L*L)
#define LP 98
#define LP2 (LP*LP)
#define LP3 (LP*LP*LP)
#define NCONV 1728   // 3*24*24 conv workgroups

typedef __attribute__((ext_vector_type(8))) short short8;
typedef __attribute__((ext_vector_type(4))) float floatx4;

__device__ __forceinline__ float eluf(float x) { return x > 0.0f ? x : expm1f(x); }

__device__ __forceinline__ unsigned short f2bf(float f) {
    __hip_bfloat16 h = __float2bfloat16(f);
    return *reinterpret_cast<unsigned short*>(&h);
}

// ---- reorder weights to Bmat[N][K=448] bf16, K = tap*16 + ch, zero-padded ----
__global__ __launch_bounds__(256) void wconv_kernel(
    const float* __restrict__ w1, const float* __restrict__ w2,
    unsigned short* __restrict__ Bm1, unsigned short* __restrict__ Bm2)
{
    int idx = blockIdx.x * 256 + threadIdx.x;
    if (idx < 16*448) {
        int o = idx / 448, k = idx % 448;
        int tau = k >> 4, i = k & 15;
        float v = (tau < 27 && i < 12) ? w1[tau*192 + i*16 + o] : 0.0f;
        Bm1[o*448 + k] = f2bf(v);
    }
    int j = idx - 16*448;
    if (j >= 0 && j < 32*448) {
        int o = j / 448, k = j % 448;
        int tau = k >> 4;
        int i = k & 15;
        float v = (tau < 27) ? w2[tau*512 + i*32 + o] : 0.0f;
        Bm2[o*448 + k] = f2bf(v);
    }
}

// ---- bonds -> padded bf16 [98^3][16] (interior only), pad chans 12-15 = 0 ----
__global__ __launch_bounds__(256) void bonds_kernel(
    const int* __restrict__ lx, const float* __restrict__ tet,
    unsigned short* __restrict__ bpad)
{
    int idx = blockIdx.x * 256 + threadIdx.x;
    int w = idx % L;
    int t = idx / L;
    int h = t % L;
    int d = t / L;

    float t00 = tet[0], t01 = tet[1], t10 = tet[2], t11 = tet[3];
    float d00 = t00*t00 + t01*t01;
    float d01 = t00*t10 + t01*t11;
    float d11 = t10*t10 + t11*t11;

    const int4 sv = *reinterpret_cast<const int4*>(lx + 4*idx);
    int s0 = sv.x, s1 = sv.y, s2 = sv.z, s3 = sv.w;
    int dm = (d == 0) ? L-1 : d-1;
    int hm = (h == 0) ? L-1 : h-1;
    int wm = (w == 0) ? L-1 : w-1;
    int r1 = lx[4*((dm*L + h)*L + w) + 1];
    int r2 = lx[4*((d*L + hm)*L + w) + 2];
    int r3 = lx[4*((d*L + h)*L + wm) + 3];

    auto dot = [&](int a, int b) -> float {
        return (a == b) ? (a ? d11 : d00) : d01;
    };

    union { unsigned short s[16]; int4 q[2]; } u;
    u.s[0]  = f2bf(dot(s0, s1));
    u.s[1]  = f2bf(dot(s0, s2));
    u.s[2]  = f2bf(dot(s0, s3));
    u.s[3]  = f2bf(dot(s0, r1));
    u.s[4]  = f2bf(dot(s0, r2));
    u.s[5]  = f2bf(dot(s0, r3));
    u.s[6]  = f2bf(dot(s1, s2));
    u.s[7]  = f2bf(dot(s2, s3));
    u.s[8]  = f2bf(dot(s3, s1));
    u.s[9]  = f2bf(dot(r1, r2));
    u.s[10] = f2bf(dot(r2, r3));
    u.s[11] = f2bf(dot(r3, r1));
    u.s[12] = 0; u.s[13] = 0; u.s[14] = 0; u.s[15] = 0;

    int pp = ((d+1)*LP + (h+1))*LP + (w+1);
    int4* dst = reinterpret_cast<int4*>(bpad + pp*16);
    dst[0] = u.q[0];
    dst[1] = u.q[1];
}

// ---- fill wrap shell of a padded [98^3][16] bf16 array from its interior ----
__global__ __launch_bounds__(256) void shell_kernel(unsigned short* __restrict__ a)
{
    int idx = blockIdx.x * 256 + threadIdx.x;
    if (idx >= LP3) return;
    int pw = idx % LP;
    int t = idx / LP;
    int ph = t % LP;
    int pd = t / LP;
    if (pd > 0 && pd < LP-1 && ph > 0 && ph < LP-1 && pw > 0 && pw < LP-1) return;
    int sd = (pd == 0) ? L : (pd == LP-1 ? 1 : pd);
    int sh = (ph == 0) ? L : (ph == LP-1 ? 1 : ph);
    int sw = (pw == 0) ? L : (pw == LP-1 ? 1 : pw);
    const int4* src = reinterpret_cast<const int4*>(a + ((sd*LP + sh)*LP + sw)*16);
    int4* dst = reinterpret_cast<int4*>(a + idx*16);
    dst[0] = src[0];
    dst[1] = src[1];
}

// ---- conv1: padded bf16 in (16ch incl pad) -> padded bf16 out (16ch), MFMA ----
__global__ __launch_bounds__(256) void conv1_kernel(
    const unsigned short* __restrict__ xpad, const unsigned short* __restrict__ Bm,
    const float* __restrict__ bias, unsigned short* __restrict__ ypad)
{
    __shared__ unsigned short tile[36*34*16];   // 6x6x34 voxels x 16ch bf16 = 39168 B
    int tid = threadIdx.x;
    int W0 = blockIdx.x * 32, H0 = blockIdx.y * 4, D0 = blockIdx.z * 4;

    for (int t = tid; t < 36*68; t += 256) {
        int row = t / 68, off = t - row*68;
        int dd = row / 6, hh = row - dd*6;
        int gi = (((D0+dd)*LP + (H0+hh))*LP + W0)*16 + off*8;
        *reinterpret_cast<int4*>(&tile[row*544 + off*8]) =
            *reinterpret_cast<const int4*>(&xpad[gi]);
    }
    __syncthreads();

    int lane = tid & 63, wave = tid >> 6;
    int laneV = lane & 15, g = lane >> 4;

    floatx4 acc[8];
    #pragma unroll
    for (int m = 0; m < 8; ++m) acc[m] = (floatx4)(0.0f);

    int moff[8];
    #pragma unroll
    for (int m = 0; m < 8; ++m) {
        int mt = wave*8 + m;
        int dd = mt >> 3, hh = (mt >> 1) & 3, half = mt & 1;
        moff[m] = ((dd*6 + hh)*34 + half*16)*16;
    }

    for (int kt = 0; kt < 14; ++kt) {
        int tau = 2*kt + (g >> 1);
        if (tau > 26) tau = 26;                 // pad half multiplies zero B
        int kd = tau / 9;
        int r  = tau - kd*9;
        int kh = r / 3;
        int kw = r - kh*3;
        int aoff = ((kd*6 + kh)*34 + kw + laneV)*16 + (g & 1)*8;
        short8 b0 = *reinterpret_cast<const short8*>(&Bm[laneV*448 + kt*32 + g*8]);
        #pragma unroll
        for (int m = 0; m < 8; ++m) {
            short8 a = *reinterpret_cast<const short8*>(&tile[moff[m] + aoff]);
            acc[m] = __builtin_amdgcn_mfma_f32_16x16x32_bf16(a, b0, acc[m], 0, 0, 0);
        }
    }

    float bch = bias[laneV];
    #pragma unroll
    for (int m = 0; m < 8; ++m) {
        int mt = wave*8 + m;
        int dd = mt >> 3, hh = (mt >> 1) & 3, half = mt & 1;
        int d = D0 + dd, h = H0 + hh;
        int wb = W0 + half*16 + g*4;            // D row = quad*4 + reg
        int pbase = (((d+1)*LP + (h+1))*LP + (wb+1))*16 + laneV;
        #pragma unroll
        for (int reg = 0; reg < 4; ++reg) {
            ypad[pbase + reg*16] = f2bf(eluf(acc[m][reg] + bch));
        }
    }
}

// ---- conv2: padded bf16 in -> fused elu + wd-dot + block reduce ----
__global__ __launch_bounds__(256) void conv2_kernel(
    const unsigned short* __restrict__ xpad, const unsigned short* __restrict__ Bm,
    const float* __restrict__ bias, const float* __restrict__ wd,
    float* __restrict__ partials)
{
    __shared__ unsigned short tile[36*34*16];
    __shared__ float red[4];
    int tid = threadIdx.x;
    int W0 = blockIdx.x * 32, H0 = blockIdx.y * 4, D0 = blockIdx.z * 4;

    for (int t = tid; t < 36*68; t += 256) {
        int row = t / 68, off = t - row*68;
        int dd = row / 6, hh = row - dd*6;
        int gi = (((D0+dd)*LP + (H0+hh))*LP + W0)*16 + off*8;
        *reinterpret_cast<int4*>(&tile[row*544 + off*8]) =
            *reinterpret_cast<const int4*>(&xpad[gi]);
    }
    __syncthreads();

    int lane = tid & 63, wave = tid >> 6;
    int laneV = lane & 15, g = lane >> 4;

    floatx4 acc[8][2];
    #pragma unroll
    for (int m = 0; m < 8; ++m) {
        acc[m][0] = (floatx4)(0.0f);
        acc[m][1] = (floatx4)(0.0f);
    }

    int moff[8];
    #pragma unroll
    for (int m = 0; m < 8; ++m) {
        int mt = wave*8 + m;
        int dd = mt >> 3, hh = (mt >> 1) & 3, half = mt & 1;
        moff[m] = ((dd*6 + hh)*34 + half*16)*16;
    }

    for (int kt = 0; kt < 14; ++kt) {
        int tau = 2*kt + (g >> 1);
        if (tau > 26) tau = 26;
        int kd = tau / 9;
        int r  = tau - kd*9;
        int kh = r / 3;
        int kw = r - kh*3;
        int aoff = ((kd*6 + kh)*34 + kw + laneV)*16 + (g & 1)*8;
        short8 b0 = *reinterpret_cast<const short8*>(&Bm[laneV*448 + kt*32 + g*8]);
        short8 b1 = *reinterpret_cast<const short8*>(&Bm[(16 + laneV)*448 + kt*32 + g*8]);
        #pragma unroll
        for (int m = 0; m < 8; ++m) {
            short8 a = *reinterpret_cast<const short8*>(&tile[moff[m] + aoff]);
            acc[m][0] = __builtin_amdgcn_mfma_f32_16x16x32_bf16(a, b0, acc[m][0], 0, 0, 0);
            acc[m][1] = __builtin_amdgcn_mfma_f32_16x16x32_bf16(a, b1, acc[m][1], 0, 0, 0);
        }
    }

    float b2a = bias[laneV], b2b = bias[16 + laneV];
    float wda = wd[laneV],  wdb = wd[16 + laneV];
    float s = 0.0f;
    #pragma unroll
    for (int m = 0; m < 8; ++m) {
        #pragma unroll
        for (int reg = 0; reg < 4; ++reg) {
            s += eluf(acc[m][0][reg] + b2a) * wda;
            s += eluf(acc[m][1][reg] + b2b) * wdb;
        }
    }

    #pragma unroll
    for (int off = 32; off; off >>= 1) s += __shfl_down(s, off);
    if (lane == 0) red[wave] = s;
    __syncthreads();
    if (tid == 0) {
        int bid = (blockIdx.z * gridDim.y + blockIdx.y) * gridDim.x + blockIdx.x;
        partials[bid] = red[0] + red[1] + red[2] + red[3];
    }
}

// ---- final reduce ----
__global__ __launch_bounds__(256) void final_kernel(
    const float* __restrict__ partials, float* __restrict__ out)
{
    float s = 0.0f;
    for (int i = threadIdx.x; i < NCONV; i += 256) s += partials[i];
    #pragma unroll
    for (int off = 32; off; off >>= 1) s += __shfl_down(s, off);
    __shared__ float red[4];
    int lane = threadIdx.x & 63;
    int wv   = threadIdx.x >> 6;
    if (lane == 0) red[wv] = s;
    __syncthreads();
    if (threadIdx.x == 0)
        out[0] = (red[0] + red[1] + red[2] + red[3]) * (1.0f / (float)L3);
}

extern "C" void kernel_launch(void* const* d_in, const int* in_sizes, int n_in,
                              void* d_out, int out_size, void* d_ws, size_t ws_size,
                              hipStream_t stream) {
    const int*   lx  = (const int*)  d_in[0];
    const float* tet = (const float*)d_in[1];
    const float* w1  = (const float*)d_in[2];
    const float* b1  = (const float*)d_in[3];
    const float* w2  = (const float*)d_in[4];
    const float* b2  = (const float*)d_in[5];
    const float* wd  = (const float*)d_in[6];
    float* out = (float*)d_out;

    char* ws = (char*)d_ws;
    const size_t PAD_BYTES = (size_t)LP3 * 16 * 2;          // 30,118,144
    unsigned short* bpad = (unsigned short*)ws;
    unsigned short* ypad = (unsigned short*)(ws + PAD_BYTES);
    unsigned short* Bm1  = (unsigned short*)(ws + 2*PAD_BYTES);
    unsigned short* Bm2  = (unsigned short*)(ws + 2*PAD_BYTES + 16*448*2);
    float* partials      = (float*)         (ws + 2*PAD_BYTES + 48*448*2);

    wconv_kernel<<<84, 256, 0, stream>>>(w1, w2, Bm1, Bm2);
    bonds_kernel<<<L3/256, 256, 0, stream>>>(lx, tet, bpad);
    shell_kernel<<<(LP3 + 255)/256, 256, 0, stream>>>(bpad);
    conv1_kernel<<<dim3(3,24,24), 256, 0, stream>>>(bpad, Bm1, b1, ypad);
    shell_kernel<<<(LP3 + 255)/256, 256, 0, stream>>>(ypad);
    conv2_kernel<<<dim3(3,24,24), 256, 0, stream>>>(ypad, Bm2, b2, wd, partials);
    final_kernel<<<1, 256, 0, stream>>>(partials, out);
}

// Round 3
// 184.250 us; speedup vs baseline: 2.8520x; 1.1074x over previous
//
#include <hip/hip_runtime.h>
#include <hip/hip_bf16.h>
#include <cmath>

#define L 96
#define L3 (L*L*L)
#define NCONV 1728   // 3*24*24 conv workgroups

typedef __attribute__((ext_vector_type(8))) short short8;
typedef __attribute__((ext_vector_type(4))) float floatx4;

__device__ __forceinline__ float eluf(float x) { return x > 0.0f ? x : expm1f(x); }

__device__ __forceinline__ unsigned short f2bf(float f) {
    __hip_bfloat16 h = __float2bfloat16(f);
    return *reinterpret_cast<unsigned short*>(&h);
}

// wrap into [0,96) for x in [-1, 97)
__device__ __forceinline__ int wrapc(int x) {
    if (x < 0) x += L;
    if (x >= L) x -= L;
    return x;
}

// ---- reorder weights to Bmat[N][K=448] bf16, K = tap*16 + ch, zero-padded ----
__global__ __launch_bounds__(256) void wconv_kernel(
    const float* __restrict__ w1, const float* __restrict__ w2,
    unsigned short* __restrict__ Bm1, unsigned short* __restrict__ Bm2)
{
    int idx = blockIdx.x * 256 + threadIdx.x;
    if (idx < 16*448) {
        int o = idx / 448, k = idx % 448;
        int tau = k >> 4, i = k & 15;
        float v = (tau < 27 && i < 12) ? w1[tau*192 + i*16 + o] : 0.0f;
        Bm1[o*448 + k] = f2bf(v);
    }
    int j = idx - 16*448;
    if (j >= 0 && j < 32*448) {
        int o = j / 448, k = j % 448;
        int tau = k >> 4;
        int i = k & 15;
        float v = (tau < 27) ? w2[tau*512 + i*32 + o] : 0.0f;
        Bm2[o*448 + k] = f2bf(v);
    }
}

// ---- bonds: spins -> unpadded bf16 [96^3][16], ch 12-15 = 0 ----
__global__ __launch_bounds__(256) void bonds_kernel(
    const int* __restrict__ lx, const float* __restrict__ tet,
    unsigned short* __restrict__ bnd)
{
    int idx = blockIdx.x * 256 + threadIdx.x;
    int w = idx % L;
    int t = idx / L;
    int h = t % L;
    int d = t / L;

    float t00 = tet[0], t01 = tet[1], t10 = tet[2], t11 = tet[3];
    float d00 = t00*t00 + t01*t01;
    float d01 = t00*t10 + t01*t11;
    float d11 = t10*t10 + t11*t11;

    const int4 sv = *reinterpret_cast<const int4*>(lx + 4*idx);
    int s0 = sv.x, s1 = sv.y, s2 = sv.z, s3 = sv.w;
    int dm = (d == 0) ? L-1 : d-1;
    int hm = (h == 0) ? L-1 : h-1;
    int wm = (w == 0) ? L-1 : w-1;
    int r1 = lx[4*((dm*L + h)*L + w) + 1];
    int r2 = lx[4*((d*L + hm)*L + w) + 2];
    int r3 = lx[4*((d*L + h)*L + wm) + 3];

    auto dot = [&](int a, int b) -> float {
        return (a == b) ? (a ? d11 : d00) : d01;
    };

    union { unsigned short s[16]; int4 q[2]; } u;
    u.s[0]  = f2bf(dot(s0, s1));
    u.s[1]  = f2bf(dot(s0, s2));
    u.s[2]  = f2bf(dot(s0, s3));
    u.s[3]  = f2bf(dot(s0, r1));
    u.s[4]  = f2bf(dot(s0, r2));
    u.s[5]  = f2bf(dot(s0, r3));
    u.s[6]  = f2bf(dot(s1, s2));
    u.s[7]  = f2bf(dot(s2, s3));
    u.s[8]  = f2bf(dot(s3, s1));
    u.s[9]  = f2bf(dot(r1, r2));
    u.s[10] = f2bf(dot(r2, r3));
    u.s[11] = f2bf(dot(r3, r1));
    u.s[12] = 0; u.s[13] = 0; u.s[14] = 0; u.s[15] = 0;

    int4* dst = reinterpret_cast<int4*>(bnd + (size_t)idx*16);
    dst[0] = u.q[0];
    dst[1] = u.q[1];
}

// ---- stage 6x6x34 halo tile (wrap handled here) from unpadded [96^3][16] ----
__device__ __forceinline__ void stage_tile(
    const unsigned short* __restrict__ x, unsigned short* __restrict__ tile,
    int W0, int H0, int D0, int tid)
{
    for (int t = tid; t < 36*68; t += 256) {
        int row = t / 68, off = t - row*68;
        int dd = row / 6, hh = row - dd*6;
        int gd = wrapc(D0 + dd - 1);
        int gh = wrapc(H0 + hh - 1);
        int vox = off >> 1, half = off & 1;
        int gw = wrapc(W0 + vox - 1);
        size_t gi = ((size_t)((gd*L + gh)*L + gw))*16 + half*8;
        *reinterpret_cast<int4*>(&tile[row*544 + off*8]) =
            *reinterpret_cast<const int4*>(&x[gi]);
    }
}

// ---- conv1: 16ch (12 live) -> 16ch, MFMA, fully unrolled K-loop ----
__global__ __launch_bounds__(256) void conv1_kernel(
    const unsigned short* __restrict__ x, const unsigned short* __restrict__ Bm,
    const float* __restrict__ bias, unsigned short* __restrict__ y)
{
    __shared__ unsigned short tile[36*34*16];   // 39168 B
    int tid = threadIdx.x;
    int W0 = blockIdx.x * 32, H0 = blockIdx.y * 4, D0 = blockIdx.z * 4;

    stage_tile(x, tile, W0, H0, D0, tid);
    __syncthreads();

    int lane = tid & 63, wave = tid >> 6;
    int laneV = lane & 15, g = lane >> 4;

    floatx4 acc[8];
    #pragma unroll
    for (int m = 0; m < 8; ++m) acc[m] = (floatx4)(0.0f);

    int moff[8];
    #pragma unroll
    for (int m = 0; m < 8; ++m) {
        int mt = wave*8 + m;
        int dd = mt >> 3, hh = (mt >> 1) & 3, half = mt & 1;
        moff[m] = ((dd*6 + hh)*34 + half*16)*16;
    }

    #pragma unroll
    for (int kt = 0; kt < 14; ++kt) {
        int tau = 2*kt + (g >> 1);
        if (tau > 26) tau = 26;                 // pad half multiplies zero B
        int kd = tau / 9;
        int r  = tau - kd*9;
        int kh = r / 3;
        int kw = r - kh*3;
        int aoff = ((kd*6 + kh)*34 + kw + laneV)*16 + (g & 1)*8;
        short8 b0 = *reinterpret_cast<const short8*>(&Bm[laneV*448 + kt*32 + g*8]);
        #pragma unroll
        for (int m = 0; m < 8; ++m) {
            short8 a = *reinterpret_cast<const short8*>(&tile[moff[m] + aoff]);
            acc[m] = __builtin_amdgcn_mfma_f32_16x16x32_bf16(a, b0, acc[m], 0, 0, 0);
        }
    }

    float bch = bias[laneV];
    #pragma unroll
    for (int m = 0; m < 8; ++m) {
        int mt = wave*8 + m;
        int dd = mt >> 3, hh = (mt >> 1) & 3, half = mt & 1;
        int d = D0 + dd, h = H0 + hh;
        int wb = W0 + half*16 + g*4;            // D row = quad*4 + reg
        size_t base = ((size_t)((d*L + h)*L + wb))*16 + laneV;
        #pragma unroll
        for (int reg = 0; reg < 4; ++reg) {
            y[base + (size_t)reg*16] = f2bf(eluf(acc[m][reg] + bch));
        }
    }
}

// ---- conv2: 16 -> 32, fused elu + wd-dot + block reduce, unrolled K-loop ----
__global__ __launch_bounds__(256) void conv2_kernel(
    const unsigned short* __restrict__ x, const unsigned short* __restrict__ Bm,
    const float* __restrict__ bias, const float* __restrict__ wd,
    float* __restrict__ partials)
{
    __shared__ unsigned short tile[36*34*16];
    __shared__ float red[4];
    int tid = threadIdx.x;
    int W0 = blockIdx.x * 32, H0 = blockIdx.y * 4, D0 = blockIdx.z * 4;

    stage_tile(x, tile, W0, H0, D0, tid);
    __syncthreads();

    int lane = tid & 63, wave = tid >> 6;
    int laneV = lane & 15, g = lane >> 4;

    floatx4 acc[8][2];
    #pragma unroll
    for (int m = 0; m < 8; ++m) {
        acc[m][0] = (floatx4)(0.0f);
        acc[m][1] = (floatx4)(0.0f);
    }

    int moff[8];
    #pragma unroll
    for (int m = 0; m < 8; ++m) {
        int mt = wave*8 + m;
        int dd = mt >> 3, hh = (mt >> 1) & 3, half = mt & 1;
        moff[m] = ((dd*6 + hh)*34 + half*16)*16;
    }

    #pragma unroll
    for (int kt = 0; kt < 14; ++kt) {
        int tau = 2*kt + (g >> 1);
        if (tau > 26) tau = 26;
        int kd = tau / 9;
        int r  = tau - kd*9;
        int kh = r / 3;
        int kw = r - kh*3;
        int aoff = ((kd*6 + kh)*34 + kw + laneV)*16 + (g & 1)*8;
        short8 b0 = *reinterpret_cast<const short8*>(&Bm[laneV*448 + kt*32 + g*8]);
        short8 b1 = *reinterpret_cast<const short8*>(&Bm[(16 + laneV)*448 + kt*32 + g*8]);
        #pragma unroll
        for (int m = 0; m < 8; ++m) {
            short8 a = *reinterpret_cast<const short8*>(&tile[moff[m] + aoff]);
            acc[m][0] = __builtin_amdgcn_mfma_f32_16x16x32_bf16(a, b0, acc[m][0], 0, 0, 0);
            acc[m][1] = __builtin_amdgcn_mfma_f32_16x16x32_bf16(a, b1, acc[m][1], 0, 0, 0);
        }
    }

    float b2a = bias[laneV], b2b = bias[16 + laneV];
    float wda = wd[laneV],  wdb = wd[16 + laneV];
    float s = 0.0f;
    #pragma unroll
    for (int m = 0; m < 8; ++m) {
        #pragma unroll
        for (int reg = 0; reg < 4; ++reg) {
            s += eluf(acc[m][0][reg] + b2a) * wda;
            s += eluf(acc[m][1][reg] + b2b) * wdb;
        }
    }

    #pragma unroll
    for (int off = 32; off; off >>= 1) s += __shfl_down(s, off);
    if (lane == 0) red[wave] = s;
    __syncthreads();
    if (tid == 0) {
        int bid = (blockIdx.z * gridDim.y + blockIdx.y) * gridDim.x + blockIdx.x;
        partials[bid] = red[0] + red[1] + red[2] + red[3];
    }
}

// ---- final reduce ----
__global__ __launch_bounds__(256) void final_kernel(
    const float* __restrict__ partials, float* __restrict__ out)
{
    float s = 0.0f;
    for (int i = threadIdx.x; i < NCONV; i += 256) s += partials[i];
    #pragma unroll
    for (int off = 32; off; off >>= 1) s += __shfl_down(s, off);
    __shared__ float red[4];
    int lane = threadIdx.x & 63;
    int wv   = threadIdx.x >> 6;
    if (lane == 0) red[wv] = s;
    __syncthreads();
    if (threadIdx.x == 0)
        out[0] = (red[0] + red[1] + red[2] + red[3]) * (1.0f / (float)L3);
}

extern "C" void kernel_launch(void* const* d_in, const int* in_sizes, int n_in,
                              void* d_out, int out_size, void* d_ws, size_t ws_size,
                              hipStream_t stream) {
    const int*   lx  = (const int*)  d_in[0];
    const float* tet = (const float*)d_in[1];
    const float* w1  = (const float*)d_in[2];
    const float* b1  = (const float*)d_in[3];
    const float* w2  = (const float*)d_in[4];
    const float* b2  = (const float*)d_in[5];
    const float* wd  = (const float*)d_in[6];
    float* out = (float*)d_out;

    char* ws = (char*)d_ws;
    const size_t ARR_BYTES = (size_t)L3 * 16 * 2;           // 28.3 MB
    unsigned short* bnd  = (unsigned short*)ws;
    unsigned short* y1   = (unsigned short*)(ws + ARR_BYTES);
    unsigned short* Bm1  = (unsigned short*)(ws + 2*ARR_BYTES);
    unsigned short* Bm2  = (unsigned short*)(ws + 2*ARR_BYTES + 16*448*2);
    float* partials      = (float*)         (ws + 2*ARR_BYTES + 48*448*2);

    wconv_kernel<<<84, 256, 0, stream>>>(w1, w2, Bm1, Bm2);
    bonds_kernel<<<L3/256, 256, 0, stream>>>(lx, tet, bnd);
    conv1_kernel<<<dim3(3,24,24), 256, 0, stream>>>(bnd, Bm1, b1, y1);
    conv2_kernel<<<dim3(3,24,24), 256, 0, stream>>>(y1, Bm2, b2, wd, partials);
    final_kernel<<<1, 256, 0, stream>>>(partials, out);
}